// Round 4
// baseline (310.912 us; speedup 1.0000x reference)
//
#include <hip/hip_runtime.h>

#define S 512
#define Dm 512

typedef __bf16 bf16x8 __attribute__((ext_vector_type(8)));
typedef float f32x4 __attribute__((ext_vector_type(4)));

// ---------------- prep: hs->bf16 (blocks 0..127) ; W->WT bf16 (blocks 128..383) ----------------
__global__ __launch_bounds__(256) void prep_kernel(
    const float* __restrict__ hs,
    const float* __restrict__ W0, const float* __restrict__ W1,
    const float* __restrict__ W2, const float* __restrict__ W3,
    __bf16* __restrict__ Abf,
    __bf16* __restrict__ T0, __bf16* __restrict__ T1,
    __bf16* __restrict__ T2, __bf16* __restrict__ T3)
{
    __shared__ __bf16 Tl[64][72];
    int u = threadIdx.x;
    if (blockIdx.x < 128) {
        int i = (blockIdx.x * 256 + u) * 8;
        float4 x0 = *(const float4*)(hs + i);
        float4 x1 = *(const float4*)(hs + i + 4);
        bf16x8 y;
        y[0] = (__bf16)x0.x; y[1] = (__bf16)x0.y; y[2] = (__bf16)x0.z; y[3] = (__bf16)x0.w;
        y[4] = (__bf16)x1.x; y[5] = (__bf16)x1.y; y[6] = (__bf16)x1.z; y[7] = (__bf16)x1.w;
        *(bf16x8*)(Abf + i) = y;
        return;
    }
    int blk = blockIdx.x - 128;
    int m = blk >> 6;
    int t = blk & 63;
    const float* W = (m == 0) ? W0 : (m == 1) ? W1 : (m == 2) ? W2 : W3;
    __bf16* T = (m == 0) ? T0 : (m == 1) ? T1 : (m == 2) ? T2 : T3;
    int k0 = (t >> 3) << 6;
    int n0 = (t & 7) << 6;
    {
        int kk = u >> 4;
        int n4 = (u & 15) << 2;
        #pragma unroll
        for (int p = 0; p < 4; ++p) {
            int k = kk + (p << 4);
            float4 wv = *(const float4*)(W + (k0 + k) * Dm + n0 + n4);
            Tl[n4 + 0][k] = (__bf16)wv.x;
            Tl[n4 + 1][k] = (__bf16)wv.y;
            Tl[n4 + 2][k] = (__bf16)wv.z;
            Tl[n4 + 3][k] = (__bf16)wv.w;
        }
    }
    __syncthreads();
    {
        int n = u >> 2;
        int ks = (u & 3) << 4;
        uint4 d0 = *(const uint4*)&Tl[n][ks];
        uint4 d1 = *(const uint4*)&Tl[n][ks + 8];
        *(uint4*)(T + (n0 + n) * Dm + k0 + ks) = d0;
        *(uint4*)(T + (n0 + n) * Dm + k0 + ks + 8) = d1;
    }
}

// ---------------- bf16 MFMA GEMM: O = A * W + bias (W given as WT[N][K]) ----------------
__global__ __launch_bounds__(256) void mfma_gemm3(
    const __bf16* __restrict__ Abf,
    const __bf16* __restrict__ T0, const __bf16* __restrict__ T1, const __bf16* __restrict__ T2,
    const float* __restrict__ b0, const float* __restrict__ b1, const float* __restrict__ b2,
    float* __restrict__ O0, float* __restrict__ O1, float* __restrict__ O2)
{
    int blk = blockIdx.x;
    int m = blk >> 6;
    int tile = blk & 63;
    const __bf16* T = (m == 0) ? T0 : (m == 1) ? T1 : T2;
    const float* bias = (m == 0) ? b0 : (m == 1) ? b1 : b2;
    float* O = (m == 0) ? O0 : (m == 1) ? O1 : O2;
    int row0 = (tile >> 3) << 6;
    int col0 = (tile & 7) << 6;

    int u = threadIdx.x;
    int w = u >> 6, lane = u & 63;
    int r = lane & 15, kg = lane >> 4;

    const __bf16* Ap  = Abf + (row0 + (w << 4) + r) * Dm + (kg << 3);
    const __bf16* Bp0 = T + (col0 + 0  + r) * Dm + (kg << 3);
    const __bf16* Bp1 = T + (col0 + 16 + r) * Dm + (kg << 3);
    const __bf16* Bp2 = T + (col0 + 32 + r) * Dm + (kg << 3);
    const __bf16* Bp3 = T + (col0 + 48 + r) * Dm + (kg << 3);

    f32x4 acc0 = {0.f, 0.f, 0.f, 0.f};
    f32x4 acc1 = acc0, acc2 = acc0, acc3 = acc0;

    #pragma unroll 4
    for (int k0 = 0; k0 < Dm; k0 += 32) {
        bf16x8 a  = *(const bf16x8*)(Ap + k0);
        bf16x8 q0 = *(const bf16x8*)(Bp0 + k0);
        bf16x8 q1 = *(const bf16x8*)(Bp1 + k0);
        bf16x8 q2 = *(const bf16x8*)(Bp2 + k0);
        bf16x8 q3 = *(const bf16x8*)(Bp3 + k0);
        acc0 = __builtin_amdgcn_mfma_f32_16x16x32_bf16(a, q0, acc0, 0, 0, 0);
        acc1 = __builtin_amdgcn_mfma_f32_16x16x32_bf16(a, q1, acc1, 0, 0, 0);
        acc2 = __builtin_amdgcn_mfma_f32_16x16x32_bf16(a, q2, acc2, 0, 0, 0);
        acc3 = __builtin_amdgcn_mfma_f32_16x16x32_bf16(a, q3, acc3, 0, 0, 0);
    }

    int orow = row0 + (w << 4) + (kg << 2);
    float bb0 = bias[col0 + 0  + r];
    float bb1 = bias[col0 + 16 + r];
    float bb2 = bias[col0 + 32 + r];
    float bb3 = bias[col0 + 48 + r];
    #pragma unroll
    for (int t = 0; t < 4; ++t) {
        O[(orow + t) * Dm + col0 + 0  + r] = acc0[t] + bb0;
        O[(orow + t) * Dm + col0 + 16 + r] = acc1[t] + bb1;
        O[(orow + t) * Dm + col0 + 32 + r] = acc2[t] + bb2;
        O[(orow + t) * Dm + col0 + 48 + r] = acc3[t] + bb3;
    }
}

// ---------------- fused attention core ----------------
// grid 512 = 8 heads * 64 i-tiles(8 rows). 256 thr = 4 waves.
// Per 128-j chunk:
//   stage KT[d][jl] (transposed K) in LDS
//   phase A: wave (ih,jw): rows ih*4..+3, j=jw*64+lane -> z' into zs[8][128], zsum partials in regs
//   phase B: wave w: rows 2w..2w+1, lane=d; acc += max(V[j][d], zs[i][j]); V direct from L1/L2
// ctx[i][d] = acc - Zsum[i]  (relu(v-z) = max(v,z)-z trick), written as bf16.
__global__ __launch_bounds__(256) void attn_fused(
    const float* __restrict__ Q, const float* __restrict__ K, const float* __restrict__ V,
    const float* __restrict__ mask, const float* __restrict__ gamma,
    const float* __restrict__ alpha, __bf16* __restrict__ ctxb)
{
    int blk = blockIdx.x;
    int h = blk >> 6;
    int it = blk & 63;
    int i0 = it << 3;
    int c0 = h << 6;

    int u = threadIdx.x;
    int w = u >> 6, lane = u & 63;
    int ih = w >> 1, jw = w & 1;

    __shared__ float KT[64][129];   // 33 KB, conflict-free both directions
    __shared__ float zs[8][128];    // 4 KB
    __shared__ float zsum2[2][8];

    float sc = 1.0f / (gamma[0] * 8.0f);
    float al = alpha[0];

    float accB[2] = {0.f, 0.f};
    float zsumA[4] = {0.f, 0.f, 0.f, 0.f};

    // ---- stage chunk 0 ----
    {
        int jl = u >> 1;
        int dh = (u & 1) << 5;
        #pragma unroll
        for (int p = 0; p < 8; ++p) {
            int d = dh + (p << 2);
            float4 kv = *(const float4*)(K + jl * Dm + c0 + d);
            KT[d + 0][jl] = kv.x; KT[d + 1][jl] = kv.y;
            KT[d + 2][jl] = kv.z; KT[d + 3][jl] = kv.w;
        }
    }

    int jl = (jw << 6) + lane;      // phase-A j within chunk
    int ibA = i0 + (ih << 2);       // phase-A rows
    int ibB = (w << 1);             // phase-B row offset within tile

    for (int ch = 0; ch < 4; ++ch) {
        __syncthreads();            // KT(ch) ready; zs free

        // ---- phase A ----
        int jg = (ch << 7) + jl;
        float madd = (1.0f - mask[jg]) * 1e6f;
        float zacc[4] = {0.f, 0.f, 0.f, 0.f};
        #pragma unroll
        for (int dc = 0; dc < 4; ++dc) {
            float kreg[16];
            #pragma unroll
            for (int t = 0; t < 16; ++t) kreg[t] = KT[(dc << 4) + t][jl];
            #pragma unroll
            for (int ii = 0; ii < 4; ++ii) {
                const float* qrow = Q + (ibA + ii) * Dm + c0 + (dc << 4);
                float a = 0.f;
                #pragma unroll
                for (int t4 = 0; t4 < 4; ++t4) {
                    float4 qv = *(const float4*)(qrow + (t4 << 2));
                    a += fabsf(kreg[(t4 << 2) + 0] - qv.x);
                    a += fabsf(kreg[(t4 << 2) + 1] - qv.y);
                    a += fabsf(kreg[(t4 << 2) + 2] - qv.z);
                    a += fabsf(kreg[(t4 << 2) + 3] - qv.w);
                }
                zacc[ii] += a;
            }
        }
        #pragma unroll
        for (int ii = 0; ii < 4; ++ii) {
            float zpv = fmaxf(zacc[ii] * sc - al, 0.0f) + madd;
            zs[(ih << 2) + ii][jl] = zpv;
            zsumA[ii] += zpv;
        }

        __syncthreads();            // zs ready; KT free

        // ---- stage chunk ch+1 (overlaps phase B) ----
        if (ch < 3) {
            int jl2 = u >> 1;
            int dh = (u & 1) << 5;
            #pragma unroll
            for (int p = 0; p < 8; ++p) {
                int d = dh + (p << 2);
                float4 kv = *(const float4*)(K + (((ch + 1) << 7) + jl2) * Dm + c0 + d);
                KT[d + 0][jl2] = kv.x; KT[d + 1][jl2] = kv.y;
                KT[d + 2][jl2] = kv.z; KT[d + 3][jl2] = kv.w;
            }
        }

        // ---- phase B ----
        {
            const float* vp = V + ((ch << 7)) * Dm + c0 + lane;
            #pragma unroll 4
            for (int jj = 0; jj < 128; ++jj) {
                float vj = vp[jj * Dm];
                accB[0] += fmaxf(vj, zs[ibB + 0][jj]);
                accB[1] += fmaxf(vj, zs[ibB + 1][jj]);
            }
        }
    }

    // ---- epilogue: reduce Zsum, write ctx ----
    #pragma unroll
    for (int ii = 0; ii < 4; ++ii) {
        float r = zsumA[ii];
        #pragma unroll
        for (int off = 32; off >= 1; off >>= 1) r += __shfl_xor(r, off, 64);
        if (lane == 0) zsum2[jw][(ih << 2) + ii] = r;
    }
    __syncthreads();
    #pragma unroll
    for (int ii = 0; ii < 2; ++ii) {
        int i = ibB + ii;
        float Z = zsum2[0][i] + zsum2[1][i];
        ctxb[(i0 + i) * Dm + c0 + lane] = (__bf16)(accB[ii] - Z);
    }
}

extern "C" void kernel_launch(void* const* d_in, const int* in_sizes, int n_in,
                              void* d_out, int out_size, void* d_ws, size_t ws_size,
                              hipStream_t stream) {
    const float* hs    = (const float*)d_in[0];
    const float* mask  = (const float*)d_in[1];
    const float* Wq    = (const float*)d_in[2];
    const float* bq    = (const float*)d_in[3];
    const float* Wk    = (const float*)d_in[4];
    const float* bk    = (const float*)d_in[5];
    const float* Wv    = (const float*)d_in[6];
    const float* bv    = (const float*)d_in[7];
    const float* Wo    = (const float*)d_in[8];
    const float* bo    = (const float*)d_in[9];
    const float* gamma = (const float*)d_in[10];
    const float* alpha = (const float*)d_in[11];
    float* out = (float*)d_out;

    char* base = (char*)d_ws;
    float*  Qb  = (float*)(base);                 // 1 MB
    float*  Kb  = Qb + S * Dm;                    // 1 MB
    float*  Vb  = Kb + S * Dm;                    // 1 MB
    __bf16* Abf = (__bf16*)(Vb + S * Dm);         // 0.5 MB
    __bf16* T0  = Abf + S * Dm;                   // 0.5 MB each
    __bf16* T1  = T0 + S * Dm;
    __bf16* T2  = T1 + S * Dm;
    __bf16* T3  = T2 + S * Dm;
    __bf16* Cbf = T3 + S * Dm;

    hipLaunchKernelGGL(prep_kernel, dim3(384), dim3(256), 0, stream,
                       hs, Wq, Wk, Wv, Wo, Abf, T0, T1, T2, T3);
    hipLaunchKernelGGL(mfma_gemm3, dim3(192), dim3(256), 0, stream,
                       Abf, T0, T1, T2, bq, bk, bv, Qb, Kb, Vb);
    hipLaunchKernelGGL(attn_fused, dim3(512), dim3(256), 0, stream,
                       Qb, Kb, Vb, mask, gamma, alpha, Cbf);
    hipLaunchKernelGGL(mfma_gemm3, dim3(64), dim3(256), 0, stream,
                       Cbf, T3, T3, T3, bo, bo, bo, out, out, out);
}

// Round 5
// 80.975 us; speedup vs baseline: 3.8396x; 3.8396x over previous
//
#include <hip/hip_runtime.h>

#define S 512
#define Dm 512

typedef __bf16 bf16x8 __attribute__((ext_vector_type(8)));
typedef float f32x4 __attribute__((ext_vector_type(4)));

// ---------------- prep: hs->bf16 (blocks 0..127) ; W->WT bf16 (blocks 128..383) ----------------
__global__ __launch_bounds__(256) void prep_kernel(
    const float* __restrict__ hs,
    const float* __restrict__ W0, const float* __restrict__ W1,
    const float* __restrict__ W2, const float* __restrict__ W3,
    __bf16* __restrict__ Abf,
    __bf16* __restrict__ T0, __bf16* __restrict__ T1,
    __bf16* __restrict__ T2, __bf16* __restrict__ T3)
{
    __shared__ __bf16 Tl[64][72];
    int u = threadIdx.x;
    if (blockIdx.x < 128) {
        int i = (blockIdx.x * 256 + u) * 8;
        float4 x0 = *(const float4*)(hs + i);
        float4 x1 = *(const float4*)(hs + i + 4);
        bf16x8 y;
        y[0] = (__bf16)x0.x; y[1] = (__bf16)x0.y; y[2] = (__bf16)x0.z; y[3] = (__bf16)x0.w;
        y[4] = (__bf16)x1.x; y[5] = (__bf16)x1.y; y[6] = (__bf16)x1.z; y[7] = (__bf16)x1.w;
        *(bf16x8*)(Abf + i) = y;
        return;
    }
    int blk = blockIdx.x - 128;
    int m = blk >> 6;
    int t = blk & 63;
    const float* W = (m == 0) ? W0 : (m == 1) ? W1 : (m == 2) ? W2 : W3;
    __bf16* T = (m == 0) ? T0 : (m == 1) ? T1 : (m == 2) ? T2 : T3;
    int k0 = (t >> 3) << 6;
    int n0 = (t & 7) << 6;
    {
        int kk = u >> 4;
        int n4 = (u & 15) << 2;
        #pragma unroll
        for (int p = 0; p < 4; ++p) {
            int k = kk + (p << 4);
            float4 wv = *(const float4*)(W + (k0 + k) * Dm + n0 + n4);
            Tl[n4 + 0][k] = (__bf16)wv.x;
            Tl[n4 + 1][k] = (__bf16)wv.y;
            Tl[n4 + 2][k] = (__bf16)wv.z;
            Tl[n4 + 3][k] = (__bf16)wv.w;
        }
    }
    __syncthreads();
    {
        int n = u >> 2;
        int ks = (u & 3) << 4;
        uint4 d0 = *(const uint4*)&Tl[n][ks];
        uint4 d1 = *(const uint4*)&Tl[n][ks + 8];
        *(uint4*)(T + (n0 + n) * Dm + k0 + ks) = d0;
        *(uint4*)(T + (n0 + n) * Dm + k0 + ks + 8) = d1;
    }
}

// ---------------- bf16 MFMA GEMM: O = A * W + bias (W given as WT[N][K]) ----------------
__global__ __launch_bounds__(256) void mfma_gemm3(
    const __bf16* __restrict__ Abf,
    const __bf16* __restrict__ T0, const __bf16* __restrict__ T1, const __bf16* __restrict__ T2,
    const float* __restrict__ b0, const float* __restrict__ b1, const float* __restrict__ b2,
    float* __restrict__ O0, float* __restrict__ O1, float* __restrict__ O2)
{
    int blk = blockIdx.x;
    int m = blk >> 6;
    int tile = blk & 63;
    const __bf16* T = (m == 0) ? T0 : (m == 1) ? T1 : T2;
    const float* bias = (m == 0) ? b0 : (m == 1) ? b1 : b2;
    float* O = (m == 0) ? O0 : (m == 1) ? O1 : O2;
    int row0 = (tile >> 3) << 6;
    int col0 = (tile & 7) << 6;

    int u = threadIdx.x;
    int w = u >> 6, lane = u & 63;
    int r = lane & 15, kg = lane >> 4;

    const __bf16* Ap  = Abf + (row0 + (w << 4) + r) * Dm + (kg << 3);
    const __bf16* Bp0 = T + (col0 + 0  + r) * Dm + (kg << 3);
    const __bf16* Bp1 = T + (col0 + 16 + r) * Dm + (kg << 3);
    const __bf16* Bp2 = T + (col0 + 32 + r) * Dm + (kg << 3);
    const __bf16* Bp3 = T + (col0 + 48 + r) * Dm + (kg << 3);

    f32x4 acc0 = {0.f, 0.f, 0.f, 0.f};
    f32x4 acc1 = acc0, acc2 = acc0, acc3 = acc0;

    #pragma unroll 4
    for (int k0 = 0; k0 < Dm; k0 += 32) {
        bf16x8 a  = *(const bf16x8*)(Ap + k0);
        bf16x8 q0 = *(const bf16x8*)(Bp0 + k0);
        bf16x8 q1 = *(const bf16x8*)(Bp1 + k0);
        bf16x8 q2 = *(const bf16x8*)(Bp2 + k0);
        bf16x8 q3 = *(const bf16x8*)(Bp3 + k0);
        acc0 = __builtin_amdgcn_mfma_f32_16x16x32_bf16(a, q0, acc0, 0, 0, 0);
        acc1 = __builtin_amdgcn_mfma_f32_16x16x32_bf16(a, q1, acc1, 0, 0, 0);
        acc2 = __builtin_amdgcn_mfma_f32_16x16x32_bf16(a, q2, acc2, 0, 0, 0);
        acc3 = __builtin_amdgcn_mfma_f32_16x16x32_bf16(a, q3, acc3, 0, 0, 0);
    }

    int orow = row0 + (w << 4) + (kg << 2);
    float bb0 = bias[col0 + 0  + r];
    float bb1 = bias[col0 + 16 + r];
    float bb2 = bias[col0 + 32 + r];
    float bb3 = bias[col0 + 48 + r];
    #pragma unroll
    for (int t = 0; t < 4; ++t) {
        O[(orow + t) * Dm + col0 + 0  + r] = acc0[t] + bb0;
        O[(orow + t) * Dm + col0 + 16 + r] = acc1[t] + bb1;
        O[(orow + t) * Dm + col0 + 32 + r] = acc2[t] + bb2;
        O[(orow + t) * Dm + col0 + 48 + r] = acc3[t] + bb3;
    }
}

// ---------------- z-pass: lane = i, Q-row in VGPRs, K broadcast from LDS ----------------
// grid 512 = 8 heads * 8 i-tiles(64) * 8 j-tiles(64). 512 thr = 8 waves; wave w: 8 j's.
// z'[i][j] -> zp (via LDS transpose, coalesced), per-lane zsum -> Zpart[h*S+i][jt].
__global__ __launch_bounds__(512) void zfast_kernel(
    const float* __restrict__ Q, const float* __restrict__ K,
    const float* __restrict__ mask, const float* __restrict__ gamma,
    const float* __restrict__ alpha,
    float* __restrict__ zp, float* __restrict__ Zpart)
{
    int blk = blockIdx.x;
    int h  = blk >> 6;
    int it = (blk >> 3) & 7;
    int jt = blk & 7;
    int i0 = it << 6;
    int j0 = jt << 6;
    int c0 = h << 6;

    int u = threadIdx.x;
    int w = u >> 6, lane = u & 63;

    __shared__ float Ks[64][68];       // [j][d], broadcast reads
    __shared__ float zsT[64][65];      // [j][i], transpose buffer
    __shared__ float partial[8][64];

    // stage K rows j0..j0+63 (coalesced)
    {
        int jr = u >> 3;               // 0..63
        int dg = (u & 7) << 3;         // 0..56
        float4 k0 = *(const float4*)(K + (j0 + jr) * Dm + c0 + dg);
        float4 k1 = *(const float4*)(K + (j0 + jr) * Dm + c0 + dg + 4);
        *(float4*)&Ks[jr][dg] = k0;
        *(float4*)&Ks[jr][dg + 4] = k1;
    }

    // per-lane Q row (row i0+lane), 64 VGPRs, static indexing
    float qreg[64];
    #pragma unroll
    for (int t = 0; t < 16; ++t) {
        float4 qv = *(const float4*)(Q + (i0 + lane) * Dm + c0 + (t << 2));
        qreg[4 * t + 0] = qv.x; qreg[4 * t + 1] = qv.y;
        qreg[4 * t + 2] = qv.z; qreg[4 * t + 3] = qv.w;
    }

    float sc = 1.0f / (gamma[0] * 8.0f);
    float al = alpha[0];

    __syncthreads();

    float zsum = 0.f;
    int jbase = w << 3;
    #pragma unroll 2
    for (int jj = 0; jj < 8; ++jj) {
        int jl = jbase + jj;
        float a0 = 0.f, a1 = 0.f, a2 = 0.f, a3 = 0.f;
        #pragma unroll
        for (int t = 0; t < 16; ++t) {
            float4 kb = *(const float4*)&Ks[jl][t << 2];   // uniform -> broadcast
            a0 += fabsf(qreg[4 * t + 0] - kb.x);
            a1 += fabsf(qreg[4 * t + 1] - kb.y);
            a2 += fabsf(qreg[4 * t + 2] - kb.z);
            a3 += fabsf(qreg[4 * t + 3] - kb.w);
        }
        float madd = (1.0f - mask[j0 + jl]) * 1e6f;
        float zpv = fmaxf((a0 + a1 + a2 + a3) * sc - al, 0.0f) + madd;
        zsT[jl][lane] = zpv;
        zsum += zpv;
    }
    partial[w][lane] = zsum;
    __syncthreads();

    if (u < 64) {
        float zs8 = 0.f;
        #pragma unroll
        for (int p = 0; p < 8; ++p) zs8 += partial[p][u];
        Zpart[((h << 9) + i0 + u) * 8 + jt] = zs8;
    }

    // transposed, coalesced zp write: thread -> row il, 8 consecutive j
    {
        int il = u >> 3;               // 0..63
        int jg = (u & 7) << 3;         // 0..56
        float* orow = zp + ((h << 9) + i0 + il) * S + j0 + jg;
        #pragma unroll
        for (int q4 = 0; q4 < 2; ++q4) {
            float4 o;
            o.x = zsT[jg + (q4 << 2) + 0][il];
            o.y = zsT[jg + (q4 << 2) + 1][il];
            o.z = zsT[jg + (q4 << 2) + 2][il];
            o.w = zsT[jg + (q4 << 2) + 3][il];
            *(float4*)(orow + (q4 << 2)) = o;
        }
    }
}

// ---------------- ctx: ctx[i][d] = sum_j max(v,z') - Zsum, bf16 out ----------------
__global__ __launch_bounds__(512) void ctx_kernel(
    const float* __restrict__ V, const float* __restrict__ zp,
    const float* __restrict__ Zpart, __bf16* __restrict__ ctxb)
{
    int blk = blockIdx.x;
    int h = blk >> 6;
    int it = blk & 63;
    int i0 = it << 3;
    int c0 = h << 6;
    int u = threadIdx.x;
    int w = u >> 6, lane = u & 63;

    __shared__ float Vt[128][64];
    __shared__ float part[8][8][64];

    float acc[8] = {};

    for (int cch = 0; cch < 4; ++cch) {
        {
            int d = u & 63;
            int jl0 = u >> 6;
            #pragma unroll
            for (int p = 0; p < 16; ++p) {
                int jl = (p << 3) + jl0;
                Vt[jl][d] = V[((cch << 7) + jl) * Dm + c0 + d];
            }
        }
        __syncthreads();

        int jbase = w << 4;
        float vv[16];
        #pragma unroll
        for (int t = 0; t < 16; ++t) vv[t] = Vt[jbase + t][lane];

        int jg = (cch << 7) + jbase;
        #pragma unroll
        for (int ii = 0; ii < 8; ++ii) {
            const float* zrow = zp + ((h * S) + (i0 + ii)) * S + jg;
            #pragma unroll
            for (int q4 = 0; q4 < 4; ++q4) {
                float4 z4 = *(const float4*)(zrow + (q4 << 2));
                float t0 = fmaxf(vv[(q4 << 2) + 0], z4.x) + fmaxf(vv[(q4 << 2) + 1], z4.y);
                float t1 = fmaxf(vv[(q4 << 2) + 2], z4.z) + fmaxf(vv[(q4 << 2) + 3], z4.w);
                acc[ii] += t0 + t1;
            }
        }
        __syncthreads();
    }

    #pragma unroll
    for (int ii = 0; ii < 8; ++ii) part[w][ii][lane] = acc[ii];
    __syncthreads();
    {
        int ii = u >> 6;
        float s = 0.f;
        #pragma unroll
        for (int ww = 0; ww < 8; ++ww) s += part[ww][ii][lane];
        float zsum = 0.f;
        const float* zpr = Zpart + ((h * S) + (i0 + ii)) * 8;
        #pragma unroll
        for (int p = 0; p < 8; ++p) zsum += zpr[p];
        ctxb[(i0 + ii) * Dm + c0 + lane] = (__bf16)(s - zsum);
    }
}

extern "C" void kernel_launch(void* const* d_in, const int* in_sizes, int n_in,
                              void* d_out, int out_size, void* d_ws, size_t ws_size,
                              hipStream_t stream) {
    const float* hs    = (const float*)d_in[0];
    const float* mask  = (const float*)d_in[1];
    const float* Wq    = (const float*)d_in[2];
    const float* bq    = (const float*)d_in[3];
    const float* Wk    = (const float*)d_in[4];
    const float* bk    = (const float*)d_in[5];
    const float* Wv    = (const float*)d_in[6];
    const float* bv    = (const float*)d_in[7];
    const float* Wo    = (const float*)d_in[8];
    const float* bo    = (const float*)d_in[9];
    const float* gamma = (const float*)d_in[10];
    const float* alpha = (const float*)d_in[11];
    float* out = (float*)d_out;

    char* base = (char*)d_ws;
    float*  zp    = (float*)(base);                               // 8 MB
    float*  Zpart = (float*)(base + (8u << 20));                  // 128 KB
    float*  Qb    = (float*)(base + (8u << 20) + (128u << 10));   // 1 MB
    float*  Kb    = Qb + S * Dm;                                  // 1 MB
    float*  Vb    = Kb + S * Dm;                                  // 1 MB
    __bf16* Abf   = (__bf16*)(Vb + S * Dm);                       // 0.5 MB
    __bf16* T0    = Abf + S * Dm;                                 // 0.5 MB each
    __bf16* T1    = T0 + S * Dm;
    __bf16* T2    = T1 + S * Dm;
    __bf16* T3    = T2 + S * Dm;
    __bf16* Cbf   = T3 + S * Dm;

    hipLaunchKernelGGL(prep_kernel, dim3(384), dim3(256), 0, stream,
                       hs, Wq, Wk, Wv, Wo, Abf, T0, T1, T2, T3);
    hipLaunchKernelGGL(mfma_gemm3, dim3(192), dim3(256), 0, stream,
                       Abf, T0, T1, T2, bq, bk, bv, Qb, Kb, Vb);
    hipLaunchKernelGGL(zfast_kernel, dim3(512), dim3(512), 0, stream,
                       Qb, Kb, mask, gamma, alpha, zp, Zpart);
    hipLaunchKernelGGL(ctx_kernel, dim3(512), dim3(512), 0, stream,
                       Vb, zp, Zpart, Cbf);
    hipLaunchKernelGGL(mfma_gemm3, dim3(64), dim3(256), 0, stream,
                       Cbf, T3, T3, T3, bo, bo, bo, out, out, out);
}

// Round 6
// 68.509 us; speedup vs baseline: 4.5383x; 1.1820x over previous
//
#include <hip/hip_runtime.h>

#define S 512
#define Dm 512

typedef __bf16 bf16x8 __attribute__((ext_vector_type(8)));
typedef float f32x4 __attribute__((ext_vector_type(4)));

// ---------------- prep: hs->bf16 (blocks 0..127) ; W->WT bf16 (blocks 128..383) ----------------
__global__ __launch_bounds__(256) void prep_kernel(
    const float* __restrict__ hs,
    const float* __restrict__ W0, const float* __restrict__ W1,
    const float* __restrict__ W2, const float* __restrict__ W3,
    __bf16* __restrict__ Abf,
    __bf16* __restrict__ T0, __bf16* __restrict__ T1,
    __bf16* __restrict__ T2, __bf16* __restrict__ T3)
{
    __shared__ __bf16 Tl[64][72];
    int u = threadIdx.x;
    if (blockIdx.x < 128) {
        int i = (blockIdx.x * 256 + u) * 8;
        float4 x0 = *(const float4*)(hs + i);
        float4 x1 = *(const float4*)(hs + i + 4);
        bf16x8 y;
        y[0] = (__bf16)x0.x; y[1] = (__bf16)x0.y; y[2] = (__bf16)x0.z; y[3] = (__bf16)x0.w;
        y[4] = (__bf16)x1.x; y[5] = (__bf16)x1.y; y[6] = (__bf16)x1.z; y[7] = (__bf16)x1.w;
        *(bf16x8*)(Abf + i) = y;
        return;
    }
    int blk = blockIdx.x - 128;
    int m = blk >> 6;
    int t = blk & 63;
    const float* W = (m == 0) ? W0 : (m == 1) ? W1 : (m == 2) ? W2 : W3;
    __bf16* T = (m == 0) ? T0 : (m == 1) ? T1 : (m == 2) ? T2 : T3;
    int k0 = (t >> 3) << 6;
    int n0 = (t & 7) << 6;
    {
        int kk = u >> 4;
        int n4 = (u & 15) << 2;
        #pragma unroll
        for (int p = 0; p < 4; ++p) {
            int k = kk + (p << 4);
            float4 wv = *(const float4*)(W + (k0 + k) * Dm + n0 + n4);
            Tl[n4 + 0][k] = (__bf16)wv.x;
            Tl[n4 + 1][k] = (__bf16)wv.y;
            Tl[n4 + 2][k] = (__bf16)wv.z;
            Tl[n4 + 3][k] = (__bf16)wv.w;
        }
    }
    __syncthreads();
    {
        int n = u >> 2;
        int ks = (u & 3) << 4;
        uint4 d0 = *(const uint4*)&Tl[n][ks];
        uint4 d1 = *(const uint4*)&Tl[n][ks + 8];
        *(uint4*)(T + (n0 + n) * Dm + k0 + ks) = d0;
        *(uint4*)(T + (n0 + n) * Dm + k0 + ks + 8) = d1;
    }
}

// ---------------- bf16 MFMA GEMM: O = A * W + bias (W given as WT[N][K]) ----------------
__global__ __launch_bounds__(256) void mfma_gemm3(
    const __bf16* __restrict__ Abf,
    const __bf16* __restrict__ T0, const __bf16* __restrict__ T1, const __bf16* __restrict__ T2,
    const float* __restrict__ b0, const float* __restrict__ b1, const float* __restrict__ b2,
    float* __restrict__ O0, float* __restrict__ O1, float* __restrict__ O2)
{
    int blk = blockIdx.x;
    int m = blk >> 6;
    int tile = blk & 63;
    const __bf16* T = (m == 0) ? T0 : (m == 1) ? T1 : T2;
    const float* bias = (m == 0) ? b0 : (m == 1) ? b1 : b2;
    float* O = (m == 0) ? O0 : (m == 1) ? O1 : O2;
    int row0 = (tile >> 3) << 6;
    int col0 = (tile & 7) << 6;

    int u = threadIdx.x;
    int w = u >> 6, lane = u & 63;
    int r = lane & 15, kg = lane >> 4;

    const __bf16* Ap  = Abf + (row0 + (w << 4) + r) * Dm + (kg << 3);
    const __bf16* Bp0 = T + (col0 + 0  + r) * Dm + (kg << 3);
    const __bf16* Bp1 = T + (col0 + 16 + r) * Dm + (kg << 3);
    const __bf16* Bp2 = T + (col0 + 32 + r) * Dm + (kg << 3);
    const __bf16* Bp3 = T + (col0 + 48 + r) * Dm + (kg << 3);

    f32x4 acc0 = {0.f, 0.f, 0.f, 0.f};
    f32x4 acc1 = acc0, acc2 = acc0, acc3 = acc0;

    #pragma unroll 4
    for (int k0 = 0; k0 < Dm; k0 += 32) {
        bf16x8 a  = *(const bf16x8*)(Ap + k0);
        bf16x8 q0 = *(const bf16x8*)(Bp0 + k0);
        bf16x8 q1 = *(const bf16x8*)(Bp1 + k0);
        bf16x8 q2 = *(const bf16x8*)(Bp2 + k0);
        bf16x8 q3 = *(const bf16x8*)(Bp3 + k0);
        acc0 = __builtin_amdgcn_mfma_f32_16x16x32_bf16(a, q0, acc0, 0, 0, 0);
        acc1 = __builtin_amdgcn_mfma_f32_16x16x32_bf16(a, q1, acc1, 0, 0, 0);
        acc2 = __builtin_amdgcn_mfma_f32_16x16x32_bf16(a, q2, acc2, 0, 0, 0);
        acc3 = __builtin_amdgcn_mfma_f32_16x16x32_bf16(a, q3, acc3, 0, 0, 0);
    }

    int orow = row0 + (w << 4) + (kg << 2);
    float bb0 = bias[col0 + 0  + r];
    float bb1 = bias[col0 + 16 + r];
    float bb2 = bias[col0 + 32 + r];
    float bb3 = bias[col0 + 48 + r];
    #pragma unroll
    for (int t = 0; t < 4; ++t) {
        O[(orow + t) * Dm + col0 + 0  + r] = acc0[t] + bb0;
        O[(orow + t) * Dm + col0 + 16 + r] = acc1[t] + bb1;
        O[(orow + t) * Dm + col0 + 32 + r] = acc2[t] + bb2;
        O[(orow + t) * Dm + col0 + 48 + r] = acc3[t] + bb3;
    }
}

// ---------------- z-pass: lane = i, Q-row in VGPRs, K via wave-uniform (scalar) loads ----------------
// grid 512 = 8 heads * 8 i-tiles(64) * 8 j-tiles(64). 512 thr = 8 waves; wave w: 8 j's.
// No LDS in the inner loop. z' -> zp via zsT transpose (coalesced), Zsum partial per lane.
__global__ __launch_bounds__(512) void zfast_kernel(
    const float* __restrict__ Q, const float* __restrict__ K,
    const float* __restrict__ mask, const float* __restrict__ gamma,
    const float* __restrict__ alpha,
    float* __restrict__ zp, float* __restrict__ Zpart)
{
    int blk = blockIdx.x;
    int h  = blk >> 6;
    int it = (blk >> 3) & 7;
    int jt = blk & 7;
    int i0 = it << 6;
    int j0 = jt << 6;
    int c0 = h << 6;

    int u = threadIdx.x;
    int w = u >> 6, lane = u & 63;

    __shared__ float zsT[64][65];      // [j][i] transpose buffer
    __shared__ float partial[8][64];

    // per-lane Q row (row i0+lane), 64 VGPRs, static indexing
    float qreg[64];
    #pragma unroll
    for (int t = 0; t < 16; ++t) {
        float4 qv = *(const float4*)(Q + (i0 + lane) * Dm + c0 + (t << 2));
        qreg[4 * t + 0] = qv.x; qreg[4 * t + 1] = qv.y;
        qreg[4 * t + 2] = qv.z; qreg[4 * t + 3] = qv.w;
    }

    float sc = 1.0f / (gamma[0] * 8.0f);
    float al = alpha[0];

    // wave-uniform j base (readfirstlane makes uniformity visible to the compiler)
    int jb = __builtin_amdgcn_readfirstlane(w << 3);

    float zsum = 0.f;
    #pragma unroll 2
    for (int jj = 0; jj < 8; ++jj) {
        const float* kr = K + (j0 + jb + jj) * Dm + c0;   // uniform pointer
        float a0 = 0.f, a1 = 0.f, a2 = 0.f, a3 = 0.f;
        #pragma unroll
        for (int t = 0; t < 16; ++t) {
            float4 kb = *(const float4*)(kr + (t << 2));  // scalar/broadcast load
            a0 += fabsf(qreg[4 * t + 0] - kb.x);
            a1 += fabsf(qreg[4 * t + 1] - kb.y);
            a2 += fabsf(qreg[4 * t + 2] - kb.z);
            a3 += fabsf(qreg[4 * t + 3] - kb.w);
        }
        float madd = (1.0f - mask[j0 + jb + jj]) * 1e6f;
        float zpv = fmaxf((a0 + a1 + a2 + a3) * sc - al, 0.0f) + madd;
        zsT[jb + jj][lane] = zpv;
        zsum += zpv;
    }
    partial[w][lane] = zsum;
    __syncthreads();

    if (u < 64) {
        float zs8 = 0.f;
        #pragma unroll
        for (int p = 0; p < 8; ++p) zs8 += partial[p][u];
        Zpart[((h << 9) + i0 + u) * 8 + jt] = zs8;
    }

    // transposed, coalesced zp write
    {
        int il = u >> 3;
        int jg = (u & 7) << 3;
        float* orow = zp + ((h << 9) + i0 + il) * S + j0 + jg;
        #pragma unroll
        for (int q4 = 0; q4 < 2; ++q4) {
            float4 o;
            o.x = zsT[jg + (q4 << 2) + 0][il];
            o.y = zsT[jg + (q4 << 2) + 1][il];
            o.z = zsT[jg + (q4 << 2) + 2][il];
            o.w = zsT[jg + (q4 << 2) + 3][il];
            *(float4*)(orow + (q4 << 2)) = o;
        }
    }
}

// ---------------- ctx: ctx[i][d] = sum_j max(v,z') - Zsum, bf16 out ----------------
// grid 512 = 8 heads * 64 i-tiles(8). 512 thr = 8 waves; lane = d.
// V direct from global (coalesced, L2-resident); z' via wave-uniform loads. No staging.
__global__ __launch_bounds__(512) void ctx_kernel(
    const float* __restrict__ V, const float* __restrict__ zp,
    const float* __restrict__ Zpart, __bf16* __restrict__ ctxb)
{
    int blk = blockIdx.x;
    int h = blk >> 6;
    int it = blk & 63;
    int i0 = it << 3;
    int c0 = h << 6;
    int u = threadIdx.x;
    int w = u >> 6, lane = u & 63;

    __shared__ float part[8][8][64];

    int wu = __builtin_amdgcn_readfirstlane(w);
    float acc[8] = {};

    #pragma unroll
    for (int cch = 0; cch < 4; ++cch) {
        int jg = (cch << 7) + (wu << 4);                  // uniform
        float vv[16];
        #pragma unroll
        for (int t = 0; t < 16; ++t)
            vv[t] = V[(jg + t) * Dm + c0 + lane];         // coalesced b32

        const float* zbase = zp + ((h * S) + i0) * S + jg; // uniform pointer
        #pragma unroll
        for (int ii = 0; ii < 8; ++ii) {
            const float* zrow = zbase + ii * S;
            #pragma unroll
            for (int q4 = 0; q4 < 4; ++q4) {
                float4 z4 = *(const float4*)(zrow + (q4 << 2));  // scalar/broadcast
                float t0 = fmaxf(vv[(q4 << 2) + 0], z4.x) + fmaxf(vv[(q4 << 2) + 1], z4.y);
                float t1 = fmaxf(vv[(q4 << 2) + 2], z4.z) + fmaxf(vv[(q4 << 2) + 3], z4.w);
                acc[ii] += t0 + t1;
            }
        }
    }

    #pragma unroll
    for (int ii = 0; ii < 8; ++ii) part[w][ii][lane] = acc[ii];
    __syncthreads();
    {
        int ii = u >> 6;
        float s = 0.f;
        #pragma unroll
        for (int ww = 0; ww < 8; ++ww) s += part[ww][ii][lane];
        float zsum = 0.f;
        const float* zpr = Zpart + ((h * S) + (i0 + ii)) * 8;
        #pragma unroll
        for (int p = 0; p < 8; ++p) zsum += zpr[p];
        ctxb[(i0 + ii) * Dm + c0 + lane] = (__bf16)(s - zsum);
    }
}

extern "C" void kernel_launch(void* const* d_in, const int* in_sizes, int n_in,
                              void* d_out, int out_size, void* d_ws, size_t ws_size,
                              hipStream_t stream) {
    const float* hs    = (const float*)d_in[0];
    const float* mask  = (const float*)d_in[1];
    const float* Wq    = (const float*)d_in[2];
    const float* bq    = (const float*)d_in[3];
    const float* Wk    = (const float*)d_in[4];
    const float* bk    = (const float*)d_in[5];
    const float* Wv    = (const float*)d_in[6];
    const float* bv    = (const float*)d_in[7];
    const float* Wo    = (const float*)d_in[8];
    const float* bo    = (const float*)d_in[9];
    const float* gamma = (const float*)d_in[10];
    const float* alpha = (const float*)d_in[11];
    float* out = (float*)d_out;

    char* base = (char*)d_ws;
    float*  zp    = (float*)(base);                               // 8 MB
    float*  Zpart = (float*)(base + (8u << 20));                  // 128 KB
    float*  Qb    = (float*)(base + (8u << 20) + (128u << 10));   // 1 MB
    float*  Kb    = Qb + S * Dm;                                  // 1 MB
    float*  Vb    = Kb + S * Dm;                                  // 1 MB
    __bf16* Abf   = (__bf16*)(Vb + S * Dm);                       // 0.5 MB
    __bf16* T0    = Abf + S * Dm;                                 // 0.5 MB each
    __bf16* T1    = T0 + S * Dm;
    __bf16* T2    = T1 + S * Dm;
    __bf16* T3    = T2 + S * Dm;
    __bf16* Cbf   = T3 + S * Dm;

    hipLaunchKernelGGL(prep_kernel, dim3(384), dim3(256), 0, stream,
                       hs, Wq, Wk, Wv, Wo, Abf, T0, T1, T2, T3);
    hipLaunchKernelGGL(mfma_gemm3, dim3(192), dim3(256), 0, stream,
                       Abf, T0, T1, T2, bq, bk, bv, Qb, Kb, Vb);
    hipLaunchKernelGGL(zfast_kernel, dim3(512), dim3(512), 0, stream,
                       Qb, Kb, mask, gamma, alpha, zp, Zpart);
    hipLaunchKernelGGL(ctx_kernel, dim3(512), dim3(512), 0, stream,
                       Vb, zp, Zpart, Cbf);
    hipLaunchKernelGGL(mfma_gemm3, dim3(64), dim3(256), 0, stream,
                       Cbf, T3, T3, T3, bo, bo, bo, out, out, out);
}